// Round 5
// baseline (331.786 us; speedup 1.0000x reference)
//
#include <hip/hip_runtime.h>
#include <stdint.h>

#define B_ 16
#define N_ 1024
#define C_ 256
#define EST 1032   // E_lds row stride in shorts (pad: 516 dw == 4 mod 32 -> 2-way max)

typedef __attribute__((ext_vector_type(8))) short short8;
typedef __attribute__((ext_vector_type(4))) float f32x4;

__device__ __forceinline__ short f2bf(float f) {
  uint32_t u = __builtin_bit_cast(uint32_t, f);
  u += 0x7fffu + ((u >> 16) & 1u);   // RNE to bf16
  return (short)(u >> 16);
}
__device__ __forceinline__ float bf2f(short s) {
  uint32_t u = ((uint32_t)(uint16_t)s) << 16;
  return __builtin_bit_cast(float, u);
}

// prelude: blocks [0,2048): cast K f32->bf16 ; blocks [2048,3072): V -> Vt bf16
__global__ __launch_bounds__(256) void prep_kernel(const float* __restrict__ K,
                                                   const float* __restrict__ V,
                                                   short* __restrict__ Kbf,
                                                   short* __restrict__ Vt) {
  int bx = blockIdx.x;
  if (bx < 2048) {
    size_t i = (size_t)bx * 256 + threadIdx.x;
    const float4* p = (const float4*)(K + i * 8);
    float4 a = p[0], b = p[1];
    short8 r;
    r[0] = f2bf(a.x); r[1] = f2bf(a.y); r[2] = f2bf(a.z); r[3] = f2bf(a.w);
    r[4] = f2bf(b.x); r[5] = f2bf(b.y); r[6] = f2bf(b.z); r[7] = f2bf(b.w);
    *(short8*)(Kbf + i * 8) = r;
  } else {
    bx -= 2048;
    __shared__ short t[64][72];
    int b = bx >> 6;
    int nb = (bx & 15) * 64;
    int cb = ((bx >> 4) & 3) * 64;
    int tx = threadIdx.x & 15;
    int ty = threadIdx.x >> 4;
#pragma unroll
    for (int i = 0; i < 4; i++) {
      int n = ty + 16 * i;
      float4 v = *(const float4*)&V[((size_t)b * N_ + nb + n) * C_ + cb + tx * 4];
      t[tx * 4 + 0][n] = f2bf(v.x);
      t[tx * 4 + 1][n] = f2bf(v.y);
      t[tx * 4 + 2][n] = f2bf(v.z);
      t[tx * 4 + 3][n] = f2bf(v.w);
    }
    __syncthreads();
    int n0 = (threadIdx.x & 7) * 8;
    int c0 = threadIdx.x >> 3;
#pragma unroll
    for (int i = 0; i < 2; i++) {
      int c = c0 + 32 * i;
      short8 s = *(const short8*)&t[c][n0];
      *(short8*)&Vt[((size_t)b * C_ + cb + c) * N_ + nb + n0] = s;
    }
  }
}

// Fused attention, streaming-S design.
// Block = 16 q rows of one batch; wave w owns k in [w*256, w*256+256), 16 tiles of 16.
// Phase 1: per k-tile: QK^T (S^T layout: lane(l15,quad) -> q=q0+l15, k=tile+quad*4+r),
//          +dis, mask, exp (NO max pass: |s|<=~6 so exp is f32-safe), bf16 -> E_lds,
//          accumulate row-sum L.  acc is 4 regs, reused per tile.
// Phase 2: p_attn = E*(1/L) f32 stores; PV from E_lds (A) x Vt (B) with 1/L in epilogue.
__global__ __launch_bounds__(256) void attn_kernel(
    const short* __restrict__ Kbf, const short* __restrict__ Vt,
    const float* __restrict__ Qf32, const float* __restrict__ dis,
    const int* __restrict__ mask, float* __restrict__ p_attn,
    float* __restrict__ p_val) {
  __shared__ short E[16 * EST];
  __shared__ float reds[4][16];

  int gid = blockIdx.x;
  int b = gid >> 6;            // 64 consecutive blocks share a batch -> K/Vt L2-hot
  int q0 = (gid & 63) * 16;
  int tid = threadIdx.x;
  int w = tid >> 6;
  int lane = tid & 63;
  int l15 = lane & 15;
  int quad = lane >> 4;

  // ---- Q fragments (once, f32 -> bf16 in reg) ----
  short8 qf[8];
  const float* Qp = Qf32 + ((size_t)b * N_ + q0 + l15) * C_ + quad * 8;
#pragma unroll
  for (int cs = 0; cs < 8; cs++) {
    float4 a = *(const float4*)(Qp + cs * 32);
    float4 c = *(const float4*)(Qp + cs * 32 + 4);
    short8 r;
    r[0] = f2bf(a.x); r[1] = f2bf(a.y); r[2] = f2bf(a.z); r[3] = f2bf(a.w);
    r[4] = f2bf(c.x); r[5] = f2bf(c.y); r[6] = f2bf(c.z); r[7] = f2bf(c.w);
    qf[cs] = r;
  }

  // ---- Phase 1: stream k-tiles ----
  const short* Kp = Kbf + ((size_t)b * N_ + w * 256) * C_;
  const float* Dp = dis + ((size_t)b * N_ + q0 + l15) * N_ + w * 256 + quad * 4;
  const int* Mp = mask + ((size_t)b * N_ + q0 + l15) * N_ + w * 256 + quad * 4;

  float Lp = 0.f;
  float4 dv[2];
  int4 mv[2];
  dv[0] = *(const float4*)(Dp);
  mv[0] = *(const int4*)(Mp);
  dv[1] = *(const float4*)(Dp + 16);
  mv[1] = *(const int4*)(Mp + 16);

#pragma unroll
  for (int kt = 0; kt < 16; kt++) {
    float4 d_c = dv[kt & 1];
    int4 m_c = mv[kt & 1];
    if (kt < 14) {   // prefetch tile kt+2
      dv[kt & 1] = *(const float4*)(Dp + (kt + 2) * 16);
      mv[kt & 1] = *(const int4*)(Mp + (kt + 2) * 16);
    }
    short8 kf[8];
#pragma unroll
    for (int cs = 0; cs < 8; cs++)
      kf[cs] = *(const short8*)(Kp + ((size_t)(kt * 16 + l15)) * C_ + cs * 32 + quad * 8);
    f32x4 acc = {0.f, 0.f, 0.f, 0.f};
#pragma unroll
    for (int cs = 0; cs < 8; cs++)
      acc = __builtin_amdgcn_mfma_f32_16x16x32_bf16(kf[cs], qf[cs], acc, 0, 0, 0);

    float e0 = m_c.x ? 0.f : __expf((acc[0] + d_c.x) * 0.0625f);
    float e1 = m_c.y ? 0.f : __expf((acc[1] + d_c.y) * 0.0625f);
    float e2 = m_c.z ? 0.f : __expf((acc[2] + d_c.z) * 0.0625f);
    float e3 = m_c.w ? 0.f : __expf((acc[3] + d_c.w) * 0.0625f);
    Lp += (e0 + e1) + (e2 + e3);
    short4 eb;
    eb.x = f2bf(e0); eb.y = f2bf(e1); eb.z = f2bf(e2); eb.w = f2bf(e3);
    *(short4*)&E[l15 * EST + w * 256 + kt * 16 + quad * 4] = eb;
  }

  Lp += __shfl_xor(Lp, 16);
  Lp += __shfl_xor(Lp, 32);
  if (lane < 16) reds[w][lane] = Lp;
  __syncthreads();

  // ---- Phase 2a: p_attn = E * (1/L) ----
  float invq = 1.0f / (reds[0][l15] + reds[1][l15] + reds[2][l15] + reds[3][l15]);
  float* Pp = p_attn + ((size_t)b * N_ + q0 + l15) * N_ + w * 256 + quad * 4;
#pragma unroll
  for (int kt = 0; kt < 16; kt++) {
    short4 eb = *(const short4*)&E[l15 * EST + w * 256 + kt * 16 + quad * 4];
    float4 p;
    p.x = bf2f(eb.x) * invq;
    p.y = bf2f(eb.y) * invq;
    p.z = bf2f(eb.z) * invq;
    p.w = bf2f(eb.w) * invq;
    *(float4*)(Pp + kt * 16) = p;
  }

  // ---- Phase 2b: PV. A = E rows (m=q), B = Vt (n=c), 1/L folded into epilogue ----
  float invo[4];
#pragma unroll
  for (int r = 0; r < 4; r++) {
    int q = quad * 4 + r;
    invo[r] = 1.0f / (reds[0][q] + reds[1][q] + reds[2][q] + reds[3][q]);
  }

  f32x4 z = {0.f, 0.f, 0.f, 0.f};
  f32x4 o[4];
#pragma unroll
  for (int i = 0; i < 4; i++) o[i] = z;
  const short* Vp = Vt + ((size_t)b * C_ + w * 64 + l15) * N_ + quad * 8;

#pragma unroll 4
  for (int ks = 0; ks < N_; ks += 32) {
    short8 a = *(const short8*)&E[l15 * EST + ks + quad * 8];
#pragma unroll
    for (int ct = 0; ct < 4; ct++) {
      short8 bv = *(const short8*)(Vp + (size_t)ct * 16 * N_ + ks);
      o[ct] = __builtin_amdgcn_mfma_f32_16x16x32_bf16(a, bv, o[ct], 0, 0, 0);
    }
  }

#pragma unroll
  for (int ct = 0; ct < 4; ct++)
#pragma unroll
    for (int r = 0; r < 4; r++)
      p_val[((size_t)b * N_ + q0 + quad * 4 + r) * C_ + w * 64 + ct * 16 + l15] =
          o[ct][r] * invo[r];
}

extern "C" void kernel_launch(void* const* d_in, const int* in_sizes, int n_in,
                              void* d_out, int out_size, void* d_ws, size_t ws_size,
                              hipStream_t stream) {
  const float* Q   = (const float*)d_in[0];
  const float* K   = (const float*)d_in[1];
  const float* V   = (const float*)d_in[2];
  const int* mask  = (const int*)d_in[3];
  const float* dis = (const float*)d_in[4];

  float* out = (float*)d_out;
  float* p_val  = out;                          // (B,N,C)
  float* p_attn = out + (size_t)B_ * N_ * C_;   // (B,N,N)

  const size_t nelem = (size_t)B_ * N_ * C_;
  short* Kbf = (short*)d_ws;
  short* Vt  = Kbf + nelem;

  prep_kernel<<<dim3(3072), 256, 0, stream>>>(K, V, Kbf, Vt);
  attn_kernel<<<dim3(B_ * (N_ / 16)), 256, 0, stream>>>(Kbf, Vt, Q, dis, mask,
                                                        p_attn, p_val);
}